// Round 1
// baseline (212.991 us; speedup 1.0000x reference)
//
#include <hip/hip_runtime.h>
#include <hip/hip_bf16.h>

#define BB 4
#define SS 4096
#define EE 1024
#define HH 64
#define NROW (BB*SS)   // 16384
#define TK 128
#define TKP (TK+8)     // 136

typedef __attribute__((ext_vector_type(8))) short short8;
typedef __attribute__((ext_vector_type(4))) short short4_t;
typedef __attribute__((ext_vector_type(4))) float f32x4;

static __device__ __forceinline__ short f2bf(float f) {
    union { float f; unsigned u; } v; v.f = f;
    unsigned r = v.u + 0x7FFFu + ((v.u >> 16) & 1u);   // RNE
    return (short)(r >> 16);
}

// ---------------- pack W: [1024][64] fp32 x3  ->  Wpack[n=192][k=1024] bf16 ----------------
__global__ __launch_bounds__(256) void pack_w(const float* __restrict__ Wq,
                                              const float* __restrict__ Wk,
                                              const float* __restrict__ Wv,
                                              short* __restrict__ Wpack) {
    int t = blockIdx.x * 256 + threadIdx.x;       // 0..196607
    int n = t % 192;
    int k = t / 192;
    const float* W = (n < 64) ? Wq : (n < 128 ? Wk : Wv);
    int nn = n & 63;
    Wpack[n * 1024 + k] = f2bf(W[k * 64 + nn]);
}

// ---------------- QKV projection: x[16384][1024] @ Wpack^T -> Q,K,V bf16 [16384][64] --------
__global__ __launch_bounds__(256) void proj_qkv(const float* __restrict__ x,
                                                const short* __restrict__ Wpack,
                                                const float* __restrict__ bq,
                                                const float* __restrict__ bk,
                                                const float* __restrict__ bv,
                                                short* __restrict__ Qg,
                                                short* __restrict__ Kg,
                                                short* __restrict__ Vg) {
    __shared__ short xs[64 * 72];     // x tile [row][k], pad to 72 (2-way bank alias = free)
    __shared__ short wsm[192 * 72];   // W tile [n][k]
    int tid  = threadIdx.x;
    int lane = tid & 63;
    int wv   = tid >> 6;              // wave 0..3, handles rows [wv*16, wv*16+16)
    int g = lane >> 4, c = lane & 15;
    int mbase = blockIdx.x * 64;

    f32x4 acc[12];
    for (int i = 0; i < 12; ++i) acc[i] = (f32x4)(0.f);

    for (int ko = 0; ko < 16; ++ko) {
        int k0 = ko * 64;
        // stage x tile: 64 rows x 64 feats, fp32 -> bf16
        for (int ps = 0; ps < 4; ++ps) {
            int idx = tid + ps * 256;
            int row = idx >> 4, c4 = idx & 15;
            float4 xv = *reinterpret_cast<const float4*>(x + (mbase + row) * 1024 + k0 + c4 * 4);
            short4_t sv;
            sv.x = f2bf(xv.x); sv.y = f2bf(xv.y); sv.z = f2bf(xv.z); sv.w = f2bf(xv.w);
            *reinterpret_cast<short4_t*>(xs + row * 72 + c4 * 4) = sv;
        }
        // stage W tile: 192 rows x 64 k
        for (int ps = 0; ps < 6; ++ps) {
            int idx = tid + ps * 256;
            int n = idx >> 3, cc = idx & 7;
            *reinterpret_cast<short8*>(wsm + n * 72 + cc * 8) =
                *reinterpret_cast<const short8*>(Wpack + n * 1024 + k0 + cc * 8);
        }
        __syncthreads();
        for (int kc = 0; kc < 2; ++kc) {
            short8 a = *reinterpret_cast<const short8*>(xs + (wv * 16 + c) * 72 + kc * 32 + g * 8);
            for (int nt = 0; nt < 12; ++nt) {
                short8 b = *reinterpret_cast<const short8*>(wsm + (nt * 16 + c) * 72 + kc * 32 + g * 8);
                acc[nt] = __builtin_amdgcn_mfma_f32_16x16x32_bf16(a, b, acc[nt], 0, 0, 0);
            }
        }
        __syncthreads();
    }
    // epilogue: add bias, store bf16 to Q/K/V
    for (int nt = 0; nt < 12; ++nt) {
        int n = nt * 16 + c;
        float bias = (n < 64) ? bq[n] : (n < 128 ? bk[n - 64] : bv[n - 128]);
        short* dst = (n < 64) ? Qg : (n < 128 ? Kg : Vg);
        int nn = n & 63;
        for (int r = 0; r < 4; ++r) {
            int row = mbase + wv * 16 + g * 4 + r;     // C-layout: row=(lane>>4)*4+reg
            dst[row * 64 + nn] = f2bf(acc[nt][r] + bias);
        }
    }
}

// ---------------- flash attention, causal, BQ=32 per block (2 waves x 16 rows) --------------
__global__ __launch_bounds__(128) void attn(const short* __restrict__ Qg,
                                            const short* __restrict__ Kg,
                                            const short* __restrict__ Vg,
                                            float* __restrict__ out) {
    __shared__ short Ks[TK * 72];        // K tile [key][feat], pad 72
    __shared__ short Vt[64 * TKP];       // V tile transposed [feat][key], pad 136
    __shared__ short Ps[2 * 16 * TKP];   // per-wave P [qrow][key]
    int tid  = threadIdx.x;
    int lane = tid & 63;
    int wv   = tid >> 6;                 // wave 0/1 -> rows [wv*16, wv*16+16)
    int g = lane >> 4, c = lane & 15;

    // balanced mapping: blocks c and c+256 (same CU under 8-XCD round robin)
    // handle causal-complementary positions w and 127-w -> const work/CU
    int bid = blockIdx.x;
    int jj  = bid & 255;
    int batch = jj >> 6;
    int w     = jj & 63;
    int p     = (bid < 256) ? w : (127 - w);
    int qbase = batch * SS + p * 32;

    // preload Q A-fragments (m=lane&15, k=(lane>>4)*8+j)
    short8 aq[2];
    for (int kc = 0; kc < 2; ++kc)
        aq[kc] = *reinterpret_cast<const short8*>(Qg + (qbase + wv * 16 + c) * 64 + kc * 32 + g * 8);

    float m_r[4], l_r[4];
    f32x4 acc_o[4];
    for (int r = 0; r < 4; ++r) { m_r[r] = -3.0e38f; l_r[r] = 0.f; }
    for (int f = 0; f < 4; ++f) acc_o[f] = (f32x4)(0.f);

    int ntiles = (p >> 2) + 1;
    short* Psw = Ps + wv * 16 * TKP;
    const float SC2 = 0.125f * 1.4426950408889634f;  // 1/sqrt(64) * log2(e)

    for (int t = 0; t < ntiles; ++t) {
        int kb = batch * SS + t * TK;
        // stage K [key][64] (b128 contiguous copies)
        for (int ps = 0; ps < 8; ++ps) {
            int idx = tid + ps * 128;
            int key = idx >> 3, cc = idx & 7;
            *reinterpret_cast<short8*>(Ks + key * 72 + cc * 8) =
                *reinterpret_cast<const short8*>(Kg + (kb + key) * 64 + cc * 8);
        }
        // stage V transposed: Vt[feat][key]
        for (int ps = 0; ps < 8; ++ps) {
            int f0 = ps * 8;
            short8 vvv = *reinterpret_cast<const short8*>(Vg + (kb + tid) * 64 + f0);
            for (int q = 0; q < 8; ++q)
                Vt[(f0 + q) * TKP + tid] = vvv[q];
        }
        __syncthreads();

        // S = Q K^T : 16 rows x 128 keys per wave
        f32x4 s[8];
        for (int nt = 0; nt < 8; ++nt) s[nt] = (f32x4)(0.f);
        for (int kc = 0; kc < 2; ++kc)
            for (int nt = 0; nt < 8; ++nt) {
                short8 bk_ = *reinterpret_cast<const short8*>(Ks + (nt * 16 + c) * 72 + kc * 32 + g * 8);
                s[nt] = __builtin_amdgcn_mfma_f32_16x16x32_bf16(aq[kc], bk_, s[nt], 0, 0, 0);
            }

        // scale + causal mask (only last tile can be partial)
        bool last = (t == ntiles - 1);
        float z[8][4];
        for (int nt = 0; nt < 8; ++nt)
            for (int r = 0; r < 4; ++r) {
                float zz = s[nt][r] * SC2;
                if (last) {
                    int keyg = t * TK + nt * 16 + c;
                    int rowg = p * 32 + wv * 16 + g * 4 + r;
                    if (keyg > rowg) zz = -3.0e38f;
                }
                z[nt][r] = zz;
            }

        // row max (reduce over key cols: nt regs + 16-lane xor shuffle)
        float alpha[4];
        for (int r = 0; r < 4; ++r) {
            float mm = z[0][r];
            for (int nt = 1; nt < 8; ++nt) mm = fmaxf(mm, z[nt][r]);
            mm = fmaxf(mm, __shfl_xor(mm, 1));
            mm = fmaxf(mm, __shfl_xor(mm, 2));
            mm = fmaxf(mm, __shfl_xor(mm, 4));
            mm = fmaxf(mm, __shfl_xor(mm, 8));
            float mn = fmaxf(m_r[r], mm);
            alpha[r] = exp2f(m_r[r] - mn);
            m_r[r] = mn;
        }

        // p = exp2(z - m), write to wave-private LDS [qrow][key], accumulate row sums
        float rs[4] = {0.f, 0.f, 0.f, 0.f};
        for (int nt = 0; nt < 8; ++nt)
            for (int r = 0; r < 4; ++r) {
                float pv = exp2f(z[nt][r] - m_r[r]);
                rs[r] += pv;
                Psw[(g * 4 + r) * TKP + nt * 16 + c] = f2bf(pv);
            }
        for (int r = 0; r < 4; ++r) {
            float ssum = rs[r];
            ssum += __shfl_xor(ssum, 1);
            ssum += __shfl_xor(ssum, 2);
            ssum += __shfl_xor(ssum, 4);
            ssum += __shfl_xor(ssum, 8);
            l_r[r] = l_r[r] * alpha[r] + ssum;
        }
        for (int f = 0; f < 4; ++f)
            for (int r = 0; r < 4; ++r) acc_o[f][r] *= alpha[r];

        // O += P V   (A = P from LDS b128, B = Vt b128)
        for (int kc2 = 0; kc2 < 4; ++kc2) {
            short8 ap = *reinterpret_cast<const short8*>(Psw + c * TKP + kc2 * 32 + g * 8);
            for (int f = 0; f < 4; ++f) {
                short8 bv_ = *reinterpret_cast<const short8*>(Vt + (f * 16 + c) * TKP + kc2 * 32 + g * 8);
                acc_o[f] = __builtin_amdgcn_mfma_f32_16x16x32_bf16(ap, bv_, acc_o[f], 0, 0, 0);
            }
        }
        __syncthreads();
    }

    // epilogue: normalize and store fp32
    for (int f = 0; f < 4; ++f)
        for (int r = 0; r < 4; ++r) {
            int row = qbase + wv * 16 + g * 4 + r;
            out[row * 64 + f * 16 + c] = acc_o[f][r] / l_r[r];
        }
}

extern "C" void kernel_launch(void* const* d_in, const int* in_sizes, int n_in,
                              void* d_out, int out_size, void* d_ws, size_t ws_size,
                              hipStream_t stream) {
    const float* x  = (const float*)d_in[0];
    const float* Wq = (const float*)d_in[1];
    const float* bq = (const float*)d_in[2];
    const float* Wk = (const float*)d_in[3];
    const float* bk = (const float*)d_in[4];
    const float* Wv = (const float*)d_in[5];
    const float* bv = (const float*)d_in[6];
    float* out = (float*)d_out;

    short* Wpack = (short*)d_ws;            // 192*1024 bf16
    short* Qg = Wpack + 192 * 1024;         // 16384*64 bf16
    short* Kg = Qg + NROW * 64;
    short* Vg = Kg + NROW * 64;

    hipLaunchKernelGGL(pack_w,   dim3(768), dim3(256), 0, stream, Wq, Wk, Wv, Wpack);
    hipLaunchKernelGGL(proj_qkv, dim3(256), dim3(256), 0, stream, x, Wpack, bq, bk, bv, Qg, Kg, Vg);
    hipLaunchKernelGGL(attn,     dim3(512), dim3(128), 0, stream, Qg, Kg, Vg, out);
}